// Round 1
// baseline (1459.618 us; speedup 1.0000x reference)
//
#include <hip/hip_runtime.h>

constexpr int N    = 50000;
constexpr int FIN  = 128;
constexpr int HID  = 256;
constexpr int NC   = 16;
constexpr int NE   = 600000;
constexpr int NPB  = 8;     // nodes per block in layer-1 GEMM

// ---------------------------------------------------------------------------
// Scatter: agg[dst[e]] += feat[src[e]] (vectorized 4 floats/thread).
// Optionally counts degree (thread with f==0).
// ---------------------------------------------------------------------------
template <int F>
__global__ __launch_bounds__(256) void k_scatter(const float* __restrict__ feat,
                                                 const int* __restrict__ srcv,
                                                 const int* __restrict__ dstv,
                                                 float* __restrict__ agg,
                                                 float* __restrict__ deg) {
    constexpr unsigned F4 = F / 4;
    unsigned idx = blockIdx.x * 256u + threadIdx.x;
    if (idx >= (unsigned)NE * F4) return;
    unsigned e  = idx / F4;          // F4 is power of two -> shift
    unsigned f  = (idx % F4) * 4;
    int s = srcv[e], d = dstv[e];
    const float4 v = *reinterpret_cast<const float4*>(&feat[(size_t)s * F + f]);
    float* ap = &agg[(size_t)d * F + f];
    atomicAdd(ap + 0, v.x);
    atomicAdd(ap + 1, v.y);
    atomicAdd(ap + 2, v.z);
    atomicAdd(ap + 3, v.w);
    if (deg != nullptr && f == 0) atomicAdd(&deg[d], 1.0f);
}

// ---------------------------------------------------------------------------
// Layer-1 GEMM: h1[n,:] = relu((agg1[n,:]/deg) @ W1_l + b1 + x[n,:] @ W1_r)
// 256 threads = 256 output cols; NPB nodes per block to amortize W traffic.
// ---------------------------------------------------------------------------
__global__ __launch_bounds__(256) void k_l1(const float* __restrict__ x,
                                            const float* __restrict__ agg,
                                            const float* __restrict__ deg,
                                            const float* __restrict__ Wl,
                                            const float* __restrict__ Wr,
                                            const float* __restrict__ b,
                                            float* __restrict__ h1) {
    __shared__ float sa[NPB][FIN];
    __shared__ float sx[NPB][FIN];
    __shared__ float sscale[NPB];
    const int t  = threadIdx.x;
    const int n0 = blockIdx.x * NPB;

    if (t < NPB) sscale[t] = 1.0f / fmaxf(deg[n0 + t], 1.0f);
    __syncthreads();

    for (int i = t; i < NPB * FIN; i += 256) {
        int ni = i >> 7, k = i & 127;
        sa[ni][k] = agg[(size_t)(n0 + ni) * FIN + k] * sscale[ni];
        sx[ni][k] = x[(size_t)(n0 + ni) * FIN + k];
    }
    __syncthreads();

    float acc[NPB];
    const float bb = b[t];
#pragma unroll
    for (int i = 0; i < NPB; ++i) acc[i] = bb;

    for (int k = 0; k < FIN; ++k) {
        const float wl = Wl[k * HID + t];
        const float wr = Wr[k * HID + t];
#pragma unroll
        for (int i = 0; i < NPB; ++i)
            acc[i] += sa[i][k] * wl + sx[i][k] * wr;
    }
#pragma unroll
    for (int i = 0; i < NPB; ++i)
        h1[(size_t)(n0 + i) * HID + t] = fmaxf(acc[i], 0.0f);
}

// ---------------------------------------------------------------------------
// y2 = h1 @ W2_l   ([N,256] @ [256,16])  — pre-multiply before scatter
// 256 threads = 16 nodes x 16 cols.
// ---------------------------------------------------------------------------
__global__ __launch_bounds__(256) void k_y2(const float* __restrict__ h1,
                                            const float* __restrict__ W,
                                            float* __restrict__ y2) {
    const int t = threadIdx.x;
    const int c = t & 15, nl = t >> 4;
    const int n = blockIdx.x * 16 + nl;
    const float* hr = &h1[(size_t)n * HID];
    float z = 0.f;
    for (int k = 0; k < HID; ++k)
        z += hr[k] * W[k * NC + c];
    y2[(size_t)n * NC + c] = z;
}

// ---------------------------------------------------------------------------
// out[n,:] = log_softmax(aggy[n,:]/deg + b2 + h1[n,:] @ W2_r)
// 256 threads = 16 nodes x 16 cols; 16-lane shuffle reductions.
// ---------------------------------------------------------------------------
__global__ __launch_bounds__(256) void k_out(const float* __restrict__ h1,
                                             const float* __restrict__ aggy,
                                             const float* __restrict__ deg,
                                             const float* __restrict__ Wr,
                                             const float* __restrict__ b,
                                             float* __restrict__ out) {
    const int t = threadIdx.x;
    const int c = t & 15, nl = t >> 4;
    const int n = blockIdx.x * 16 + nl;
    const float scale = 1.0f / fmaxf(deg[n], 1.0f);
    const float* hr = &h1[(size_t)n * HID];
    float z = aggy[(size_t)n * NC + c] * scale + b[c];
    for (int k = 0; k < HID; ++k)
        z += hr[k] * Wr[k * NC + c];

    float m = z;
    for (int off = 1; off < 16; off <<= 1)
        m = fmaxf(m, __shfl_xor(m, off, 16));
    float ex = expf(z - m);
    float s = ex;
    for (int off = 1; off < 16; off <<= 1)
        s += __shfl_xor(s, off, 16);
    out[(size_t)n * NC + c] = (z - m) - logf(s);
}

// ---------------------------------------------------------------------------
extern "C" void kernel_launch(void* const* d_in, const int* in_sizes, int n_in,
                              void* d_out, int out_size, void* d_ws, size_t ws_size,
                              hipStream_t stream) {
    const float* x   = (const float*)d_in[0];
    const int*   ei  = (const int*)d_in[1];     // int32 on device (JAX x64 off)
    const int*   srcv = ei;
    const int*   dstv = ei + NE;
    const float* W1l = (const float*)d_in[2];
    const float* W1r = (const float*)d_in[3];
    const float* b1  = (const float*)d_in[4];
    const float* W2l = (const float*)d_in[5];
    const float* W2r = (const float*)d_in[6];
    const float* b2  = (const float*)d_in[7];
    float* out = (float*)d_out;

    // workspace layout (floats)
    float* ws   = (float*)d_ws;
    float* deg  = ws;                              // 50,000
    float* agg1 = ws + 50000;                      // 6,400,000
    float* aggy = agg1 + (size_t)N * FIN;          //   800,000
    float* h1   = aggy + (size_t)N * NC;           // 12,800,000
    float* y2   = h1 + (size_t)N * HID;            //   800,000
    // total: 20,850,000 floats = 83.4 MB

    // zero the accumulated regions (deg, agg1, aggy are contiguous)
    hipMemsetAsync(deg, 0, (size_t)(50000 + (size_t)N * FIN + (size_t)N * NC) * sizeof(float), stream);

    // layer 1: scatter x, then GEMM + relu
    {
        unsigned total = (unsigned)NE * (FIN / 4);
        k_scatter<FIN><<<(total + 255) / 256, 256, 0, stream>>>(x, srcv, dstv, agg1, deg);
    }
    k_l1<<<N / NPB, 256, 0, stream>>>(x, agg1, deg, W1l, W1r, b1, h1);

    // layer 2: pre-multiply by W2_l (256->16), scatter only 16-dim, fuse rest
    k_y2<<<N / 16, 256, 0, stream>>>(h1, W2l, y2);
    {
        unsigned total = (unsigned)NE * (NC / 4);
        k_scatter<NC><<<(total + 255) / 256, 256, 0, stream>>>(y2, srcv, dstv, aggy, nullptr);
    }
    k_out<<<N / 16, 256, 0, stream>>>(h1, aggy, deg, W2r, b2, out);
}

// Round 2
// 563.374 us; speedup vs baseline: 2.5909x; 2.5909x over previous
//
#include <hip/hip_runtime.h>

constexpr int N    = 50000;
constexpr int FIN  = 128;
constexpr int HID  = 256;
constexpr int NC   = 16;
constexpr int NE   = 600000;
constexpr int NPB  = 8;     // nodes per block in layer-1 GEMM

// ---------------------------------------------------------------------------
// Histogram of dst degrees (counting-sort pass 1).
// ---------------------------------------------------------------------------
__global__ __launch_bounds__(256) void k_hist(const int* __restrict__ dstv,
                                              unsigned* __restrict__ cnt) {
    unsigned e = blockIdx.x * 256u + threadIdx.x;
    if (e < (unsigned)NE) atomicAdd(&cnt[dstv[e]], 1u);
}

// ---------------------------------------------------------------------------
// Exclusive scan of 50k counts in one block; emits rowptr, cursor copy,
// and scale = 1/max(deg,1).
// ---------------------------------------------------------------------------
__global__ __launch_bounds__(1024) void k_scan(const unsigned* __restrict__ cnt,
                                               unsigned* __restrict__ rowptr,
                                               unsigned* __restrict__ cursor,
                                               float* __restrict__ scale) {
    __shared__ unsigned ssum[1024];
    const int t  = threadIdx.x;
    const int CH = (N + 1023) / 1024;          // 49
    const int lo = t * CH;
    const int hi = min(lo + CH, N);

    unsigned s = 0;
    for (int i = lo; i < hi; ++i) s += cnt[i];
    ssum[t] = s;
    __syncthreads();
    for (int off = 1; off < 1024; off <<= 1) {
        unsigned v = 0;
        if (t >= off) v = ssum[t - off];
        __syncthreads();
        if (t >= off) ssum[t] += v;
        __syncthreads();
    }
    unsigned run = (t > 0) ? ssum[t - 1] : 0;
    for (int i = lo; i < hi; ++i) {
        unsigned c = cnt[i];
        rowptr[i] = run;
        cursor[i] = run;
        scale[i]  = 1.0f / fmaxf((float)c, 1.0f);
        run += c;
    }
    if (t == 1023) rowptr[N] = ssum[1023];
}

// ---------------------------------------------------------------------------
// Counting-sort pass 2: place src of each edge into its dst segment.
// ---------------------------------------------------------------------------
__global__ __launch_bounds__(256) void k_place(const int* __restrict__ srcv,
                                               const int* __restrict__ dstv,
                                               unsigned* __restrict__ cursor,
                                               int* __restrict__ srcs) {
    unsigned e = blockIdx.x * 256u + threadIdx.x;
    if (e >= (unsigned)NE) return;
    unsigned pos = atomicAdd(&cursor[dstv[e]], 1u);
    srcs[pos] = srcv[e];
}

// ---------------------------------------------------------------------------
// Layer-1 aggregation (gather, no atomics): one wave per node, lane = 2 cols.
// agg[n,:] = scale[n] * sum_{e in seg(n)} x[srcs[e], :]
// ---------------------------------------------------------------------------
__global__ __launch_bounds__(256) void k_agg1(const float* __restrict__ x,
                                              const int* __restrict__ srcs,
                                              const unsigned* __restrict__ rowptr,
                                              const float* __restrict__ scale,
                                              float* __restrict__ agg) {
    const unsigned wid  = (blockIdx.x * 256u + threadIdx.x) >> 6;   // node
    const unsigned lane = threadIdx.x & 63;
    if (wid >= (unsigned)N) return;
    const unsigned lo = rowptr[wid], hi = rowptr[wid + 1];
    float2 acc = {0.f, 0.f};
    for (unsigned e = lo; e < hi; ++e) {
        const int s = srcs[e];
        const float2 v = *reinterpret_cast<const float2*>(&x[(size_t)s * FIN + lane * 2]);
        acc.x += v.x;
        acc.y += v.y;
    }
    const float sc = scale[wid];
    acc.x *= sc;
    acc.y *= sc;
    *reinterpret_cast<float2*>(&agg[(size_t)wid * FIN + lane * 2]) = acc;
}

// ---------------------------------------------------------------------------
// Layer-1 GEMM: h1[n,:] = relu(agg[n,:] @ W1_l + b1 + x[n,:] @ W1_r)
// (agg pre-normalized). 256 threads = 256 cols; NPB nodes per block.
// ---------------------------------------------------------------------------
__global__ __launch_bounds__(256) void k_l1(const float* __restrict__ x,
                                            const float* __restrict__ agg,
                                            const float* __restrict__ Wl,
                                            const float* __restrict__ Wr,
                                            const float* __restrict__ b,
                                            float* __restrict__ h1) {
    __shared__ float sa[NPB][FIN];
    __shared__ float sx[NPB][FIN];
    const int t  = threadIdx.x;
    const int n0 = blockIdx.x * NPB;

    for (int i = t; i < NPB * FIN; i += 256) {
        int ni = i >> 7, k = i & 127;
        sa[ni][k] = agg[(size_t)(n0 + ni) * FIN + k];
        sx[ni][k] = x[(size_t)(n0 + ni) * FIN + k];
    }
    __syncthreads();

    float acc[NPB];
    const float bb = b[t];
#pragma unroll
    for (int i = 0; i < NPB; ++i) acc[i] = bb;

    for (int k = 0; k < FIN; ++k) {
        const float wl = Wl[k * HID + t];
        const float wr = Wr[k * HID + t];
#pragma unroll
        for (int i = 0; i < NPB; ++i)
            acc[i] += sa[i][k] * wl + sx[i][k] * wr;
    }
#pragma unroll
    for (int i = 0; i < NPB; ++i)
        h1[(size_t)(n0 + i) * HID + t] = fmaxf(acc[i], 0.0f);
}

// ---------------------------------------------------------------------------
// y2 = h1 @ W2_l   ([N,256] @ [256,16]) — pre-multiply before aggregation.
// ---------------------------------------------------------------------------
__global__ __launch_bounds__(256) void k_y2(const float* __restrict__ h1,
                                            const float* __restrict__ W,
                                            float* __restrict__ y2) {
    const int t = threadIdx.x;
    const int c = t & 15, nl = t >> 4;
    const int n = blockIdx.x * 16 + nl;
    const float* hr = &h1[(size_t)n * HID];
    float z = 0.f;
    for (int k = 0; k < HID; ++k)
        z += hr[k] * W[k * NC + c];
    y2[(size_t)n * NC + c] = z;
}

// ---------------------------------------------------------------------------
// out[n,:] = log_softmax(gather(y2)/deg + b2 + h1[n,:] @ W2_r)
// Layer-2 aggregation fused in (16-lane gather per node).
// ---------------------------------------------------------------------------
__global__ __launch_bounds__(256) void k_out(const float* __restrict__ h1,
                                             const float* __restrict__ y2,
                                             const int* __restrict__ srcs,
                                             const unsigned* __restrict__ rowptr,
                                             const float* __restrict__ scale,
                                             const float* __restrict__ Wr,
                                             const float* __restrict__ b,
                                             float* __restrict__ out) {
    const int t = threadIdx.x;
    const int c = t & 15, nl = t >> 4;
    const int n = blockIdx.x * 16 + nl;
    const unsigned lo = rowptr[n], hi = rowptr[n + 1];
    float g = 0.f;
    for (unsigned e = lo; e < hi; ++e) {
        const int s = srcs[e];
        g += y2[(size_t)s * NC + c];
    }
    float z = g * scale[n] + b[c];
    const float* hr = &h1[(size_t)n * HID];
    for (int k = 0; k < HID; ++k)
        z += hr[k] * Wr[k * NC + c];

    float m = z;
    for (int off = 1; off < 16; off <<= 1)
        m = fmaxf(m, __shfl_xor(m, off, 16));
    float ex = expf(z - m);
    float s = ex;
    for (int off = 1; off < 16; off <<= 1)
        s += __shfl_xor(s, off, 16);
    out[(size_t)n * NC + c] = (z - m) - logf(s);
}

// ---------------------------------------------------------------------------
extern "C" void kernel_launch(void* const* d_in, const int* in_sizes, int n_in,
                              void* d_out, int out_size, void* d_ws, size_t ws_size,
                              hipStream_t stream) {
    const float* x    = (const float*)d_in[0];
    const int*   ei   = (const int*)d_in[1];    // int32 on device (JAX x64 off)
    const int*   srcv = ei;
    const int*   dstv = ei + NE;
    const float* W1l  = (const float*)d_in[2];
    const float* W1r  = (const float*)d_in[3];
    const float* b1   = (const float*)d_in[4];
    const float* W2l  = (const float*)d_in[5];
    const float* W2r  = (const float*)d_in[6];
    const float* b2   = (const float*)d_in[7];
    float* out = (float*)d_out;

    // workspace layout (4-byte units); float2 users 8B-aligned
    float*    ws     = (float*)d_ws;
    float*    scale  = ws;                                   //    50,000
    unsigned* cnt    = (unsigned*)(ws + 50000);              //    50,000
    unsigned* rowptr = (unsigned*)(ws + 100000);             //    50,002 (padded)
    unsigned* cursor = (unsigned*)(ws + 150002);             //    50,000
    int*      srcs   = (int*)(ws + 200002);                  //   600,000
    float*    agg1   = ws + 800002;                          // 6,400,000
    float*    h1     = ws + 7200002;                         // 12,800,000
    float*    y2     = agg1;                                 // alias: agg1 dead after k_l1
    // total: 20,000,002 floats = 80.0 MB

    hipMemsetAsync(cnt, 0, (size_t)N * sizeof(unsigned), stream);

    const int EB = (NE + 255) / 256;
    k_hist <<<EB, 256, 0, stream>>>(dstv, cnt);
    k_scan <<<1, 1024, 0, stream>>>(cnt, rowptr, cursor, scale);
    k_place<<<EB, 256, 0, stream>>>(srcv, dstv, cursor, srcs);

    k_agg1<<<(N * 64 + 255) / 256, 256, 0, stream>>>(x, srcs, rowptr, scale, agg1);
    k_l1  <<<N / NPB, 256, 0, stream>>>(x, agg1, W1l, W1r, b1, h1);

    k_y2  <<<N / 16, 256, 0, stream>>>(h1, W2l, y2);
    k_out <<<N / 16, 256, 0, stream>>>(h1, y2, srcs, rowptr, scale, W2r, b2, out);
}

// Round 3
// 384.323 us; speedup vs baseline: 3.7979x; 1.4659x over previous
//
#include <hip/hip_runtime.h>
#include <hip/hip_bf16.h>

constexpr int N    = 50000;
constexpr int NPAD = 50048;          // padded to 64-row tiles (782*64)
constexpr int FIN  = 128;
constexpr int HID  = 256;
constexpr int NC   = 16;
constexpr int NE   = 600000;

using bf16x8 = __attribute__((ext_vector_type(8))) short;
using f32x4  = __attribute__((ext_vector_type(4))) float;

__device__ inline float bf2f(unsigned short u) {
    union { unsigned int i; float f; } v; v.i = (unsigned)u << 16; return v.f;
}
__device__ inline unsigned short f2bf(float f) {
    __hip_bfloat16 h = __float2bfloat16(f);
    return __builtin_bit_cast(unsigned short, h);
}

// ---------------------------------------------------------------------------
// Counting sort (CSR by dst): hist -> scan -> place.
// ---------------------------------------------------------------------------
__global__ __launch_bounds__(256) void k_hist(const int* __restrict__ dstv,
                                              unsigned* __restrict__ cnt) {
    unsigned e = blockIdx.x * 256u + threadIdx.x;
    if (e < (unsigned)NE) atomicAdd(&cnt[dstv[e]], 1u);
}

__global__ __launch_bounds__(1024) void k_scan(const unsigned* __restrict__ cnt,
                                               unsigned* __restrict__ rowptr,
                                               unsigned* __restrict__ cursor,
                                               float* __restrict__ scale) {
    __shared__ unsigned ssum[1024];
    const int t  = threadIdx.x;
    const int CH = (N + 1023) / 1024;
    const int lo = t * CH;
    const int hi = min(lo + CH, N);

    unsigned s = 0;
    for (int i = lo; i < hi; ++i) s += cnt[i];
    ssum[t] = s;
    __syncthreads();
    for (int off = 1; off < 1024; off <<= 1) {
        unsigned v = 0;
        if (t >= off) v = ssum[t - off];
        __syncthreads();
        if (t >= off) ssum[t] += v;
        __syncthreads();
    }
    unsigned run = (t > 0) ? ssum[t - 1] : 0;
    for (int i = lo; i < hi; ++i) {
        unsigned c = cnt[i];
        rowptr[i] = run;
        cursor[i] = run;
        scale[i]  = 1.0f / fmaxf((float)c, 1.0f);
        run += c;
    }
    if (t == 1023) rowptr[N] = ssum[1023];
}

__global__ __launch_bounds__(256) void k_place(const int* __restrict__ srcv,
                                               const int* __restrict__ dstv,
                                               unsigned* __restrict__ cursor,
                                               int* __restrict__ srcs) {
    unsigned e = blockIdx.x * 256u + threadIdx.x;
    if (e >= (unsigned)NE) return;
    unsigned pos = atomicAdd(&cursor[dstv[e]], 1u);
    srcs[pos] = srcv[e];
}

// ---------------------------------------------------------------------------
// x (f32) -> xb (bf16), 8 elems/thread. Grid covers exactly N*FIN/8.
// ---------------------------------------------------------------------------
__global__ __launch_bounds__(256) void k_castx(const float* __restrict__ x,
                                               unsigned short* __restrict__ xb) {
    size_t idx = (size_t)blockIdx.x * 256u + threadIdx.x;
    const float4 v0 = *reinterpret_cast<const float4*>(&x[idx * 8]);
    const float4 v1 = *reinterpret_cast<const float4*>(&x[idx * 8 + 4]);
    bf16x8 o;
    o[0] = (short)f2bf(v0.x); o[1] = (short)f2bf(v0.y);
    o[2] = (short)f2bf(v0.z); o[3] = (short)f2bf(v0.w);
    o[4] = (short)f2bf(v1.x); o[5] = (short)f2bf(v1.y);
    o[6] = (short)f2bf(v1.z); o[7] = (short)f2bf(v1.w);
    *reinterpret_cast<bf16x8*>(&xb[idx * 8]) = o;
}

// ---------------------------------------------------------------------------
// Pack W1l/W1r (f32 [128][256]) into MFMA operand order (bf16):
// Wp[((kk*256 + c)*4 + g)*8 + b] = W[(kk*32 + g*8 + b)][c]
// ---------------------------------------------------------------------------
__global__ __launch_bounds__(256) void k_packW(const float* __restrict__ Wl,
                                               const float* __restrict__ Wr,
                                               unsigned short* __restrict__ Wlp,
                                               unsigned short* __restrict__ Wrp) {
    unsigned id = blockIdx.x * 256u + threadIdx.x;    // 8192 total
    unsigned mat = id >> 12, kk = (id >> 10) & 3, c = (id >> 2) & 255, g = id & 3;
    const float* src = mat ? Wr : Wl;
    unsigned short* dst = mat ? Wrp : Wlp;
    bf16x8 o;
#pragma unroll
    for (int b = 0; b < 8; ++b)
        o[b] = (short)f2bf(src[(kk * 32 + g * 8 + b) * HID + c]);
    *reinterpret_cast<bf16x8*>(&dst[((kk * 256u + c) * 4u + g) * 8u]) = o;
}

// ---------------------------------------------------------------------------
// Layer-1 aggregation (gather): one wave per node, lane = 2 bf16 cols.
// ---------------------------------------------------------------------------
__global__ __launch_bounds__(256) void k_agg1(const unsigned short* __restrict__ xb,
                                              const int* __restrict__ srcs,
                                              const unsigned* __restrict__ rowptr,
                                              const float* __restrict__ scale,
                                              unsigned short* __restrict__ aggb) {
    const unsigned wid  = (blockIdx.x * 256u + threadIdx.x) >> 6;
    const unsigned lane = threadIdx.x & 63;
    if (wid >= (unsigned)N) return;
    const unsigned lo = rowptr[wid], hi = rowptr[wid + 1];
    float ax = 0.f, ay = 0.f;
    for (unsigned e = lo; e < hi; ++e) {
        const int s = srcs[e];
        unsigned v = *reinterpret_cast<const unsigned*>(&xb[(size_t)s * FIN + lane * 2]);
        ax += bf2f((unsigned short)(v & 0xffffu));
        ay += bf2f((unsigned short)(v >> 16));
    }
    const float sc = scale[wid];
    unsigned ov = (unsigned)f2bf(ax * sc) | ((unsigned)f2bf(ay * sc) << 16);
    *reinterpret_cast<unsigned*>(&aggb[(size_t)wid * FIN + lane * 2]) = ov;
}

// ---------------------------------------------------------------------------
// Layer-1 MFMA GEMM: h1 = relu(agg@W1l + x@W1r + b1), bf16 in/out, f32 acc.
// Block: 64 rows x 256 cols, 4 waves (each 64 cols). A staged in LDS with
// 16B-chunk XOR swizzle (2-way banks). k-permutation sigma(g,b)=8g+b applied
// identically to A and B (contraction is invariant to common k-perm).
// ---------------------------------------------------------------------------
__global__ __launch_bounds__(256) void k_l1m(const unsigned short* __restrict__ aggb,
                                             const unsigned short* __restrict__ xb,
                                             const unsigned short* __restrict__ Wlp,
                                             const unsigned short* __restrict__ Wrp,
                                             const float* __restrict__ b1,
                                             unsigned short* __restrict__ h1b) {
    __shared__ short sA[2][64 * FIN];
    const int t = threadIdx.x;
    const int wave = t >> 6, lane = t & 63;
    const int g = lane >> 4, lr = lane & 15;
    const size_t row0 = (size_t)blockIdx.x * 64;

    for (int mat = 0; mat < 2; ++mat) {
        const unsigned short* src = mat ? xb : aggb;
        for (int i = t; i < 64 * 16; i += 256) {
            int r = i >> 4, c = i & 15;
            bf16x8 v = *reinterpret_cast<const bf16x8*>(&src[(row0 + r) * FIN + c * 8]);
            int dc = c ^ (r & 7);
            *reinterpret_cast<bf16x8*>(&sA[mat][r * FIN + dc * 8]) = v;
        }
    }
    __syncthreads();

    f32x4 acc[4][4];
#pragma unroll
    for (int m = 0; m < 4; ++m)
#pragma unroll
        for (int n = 0; n < 4; ++n) acc[m][n] = (f32x4){0.f, 0.f, 0.f, 0.f};

#pragma unroll
    for (int kk = 0; kk < 4; ++kk) {
        bf16x8 bL[4], bR[4];
#pragma unroll
        for (int n = 0; n < 4; ++n) {
            int col = wave * 64 + n * 16 + lr;
            size_t off = ((size_t)(kk * 256 + col) * 4 + g) * 8;
            bL[n] = *reinterpret_cast<const bf16x8*>(&Wlp[off]);
            bR[n] = *reinterpret_cast<const bf16x8*>(&Wrp[off]);
        }
        bf16x8 aA[4], aX[4];
        const int chunk = (kk * 4 + g) ^ (lr & 7);
#pragma unroll
        for (int m = 0; m < 4; ++m) {
            int r = m * 16 + lr;
            aA[m] = *reinterpret_cast<const bf16x8*>(&sA[0][r * FIN + chunk * 8]);
            aX[m] = *reinterpret_cast<const bf16x8*>(&sA[1][r * FIN + chunk * 8]);
        }
#pragma unroll
        for (int m = 0; m < 4; ++m)
#pragma unroll
            for (int n = 0; n < 4; ++n) {
                acc[m][n] = __builtin_amdgcn_mfma_f32_16x16x32_bf16(aA[m], bL[n], acc[m][n], 0, 0, 0);
                acc[m][n] = __builtin_amdgcn_mfma_f32_16x16x32_bf16(aX[m], bR[n], acc[m][n], 0, 0, 0);
            }
    }

    // epilogue: +bias, relu, bf16 store. C/D map (m89): col=lane&15, row=4*(lane>>4)+reg
#pragma unroll
    for (int n = 0; n < 4; ++n) {
        int col = wave * 64 + n * 16 + lr;
        float bb = b1[col];
#pragma unroll
        for (int m = 0; m < 4; ++m) {
#pragma unroll
            for (int reg = 0; reg < 4; ++reg) {
                size_t r = row0 + m * 16 + g * 4 + reg;
                float z = acc[m][n][reg] + bb;
                h1b[r * HID + col] = f2bf(fmaxf(z, 0.f));
            }
        }
    }
}

// ---------------------------------------------------------------------------
// y2 = h1 @ W2_l   ([N,256]bf16 @ [256,16]f32)
// ---------------------------------------------------------------------------
__global__ __launch_bounds__(256) void k_y2(const unsigned short* __restrict__ h1b,
                                            const float* __restrict__ W,
                                            float* __restrict__ y2) {
    const int t = threadIdx.x, c = t & 15, nl = t >> 4;
    const size_t n = (size_t)blockIdx.x * 16 + nl;
    const unsigned short* hr = &h1b[n * HID];
    float z = 0.f;
    for (int k = 0; k < HID; ++k) z += bf2f(hr[k]) * W[k * NC + c];
    y2[n * NC + c] = z;
}

// ---------------------------------------------------------------------------
// out = log_softmax(gather(y2)/deg + b2 + h1@W2_r), layer-2 agg fused.
// ---------------------------------------------------------------------------
__global__ __launch_bounds__(256) void k_out(const unsigned short* __restrict__ h1b,
                                             const float* __restrict__ y2,
                                             const int* __restrict__ srcs,
                                             const unsigned* __restrict__ rowptr,
                                             const float* __restrict__ scale,
                                             const float* __restrict__ Wr,
                                             const float* __restrict__ b,
                                             float* __restrict__ out) {
    const int t = threadIdx.x, c = t & 15, nl = t >> 4;
    const size_t n = (size_t)blockIdx.x * 16 + nl;
    const unsigned lo = rowptr[n], hi = rowptr[n + 1];
    float gsum = 0.f;
    for (unsigned e = lo; e < hi; ++e)
        gsum += y2[(size_t)srcs[e] * NC + c];
    float z = gsum * scale[n] + b[c];
    const unsigned short* hr = &h1b[n * HID];
    for (int k = 0; k < HID; ++k)
        z += bf2f(hr[k]) * Wr[k * NC + c];

    float m = z;
    for (int off = 1; off < 16; off <<= 1)
        m = fmaxf(m, __shfl_xor(m, off, 16));
    float ex = expf(z - m);
    float s = ex;
    for (int off = 1; off < 16; off <<= 1)
        s += __shfl_xor(s, off, 16);
    out[n * NC + c] = (z - m) - logf(s);
}

// ---------------------------------------------------------------------------
extern "C" void kernel_launch(void* const* d_in, const int* in_sizes, int n_in,
                              void* d_out, int out_size, void* d_ws, size_t ws_size,
                              hipStream_t stream) {
    const float* x    = (const float*)d_in[0];
    const int*   ei   = (const int*)d_in[1];    // int32 on device (JAX x64 off)
    const int*   srcv = ei;
    const int*   dstv = ei + NE;
    const float* W1l  = (const float*)d_in[2];
    const float* W1r  = (const float*)d_in[3];
    const float* b1   = (const float*)d_in[4];
    const float* W2l  = (const float*)d_in[5];
    const float* W2r  = (const float*)d_in[6];
    const float* b2   = (const float*)d_in[7];
    float* out = (float*)d_out;

    // workspace layout (float offsets; all bf16x8 users 16B-aligned)
    float*          ws     = (float*)d_ws;
    float*          scale  = ws;                               //    50,000
    unsigned*       cnt    = (unsigned*)(ws + 50000);          //    50,000
    unsigned*       rowptr = (unsigned*)(ws + 100000);         //    50,004 (pad)
    unsigned*       cursor = (unsigned*)(ws + 150004);         //    50,000
    int*            srcs   = (int*)(ws + 200004);              //   600,000 (+4 align)
    unsigned short* xb     = (unsigned short*)(ws + 800008);   // NPAD*128 bf16 = 3,203,072 f
    unsigned short* aggb   = (unsigned short*)(ws + 4003080);  // NPAD*128 bf16
    unsigned short* Wlp    = (unsigned short*)(ws + 7206152);  // 32768 bf16 = 16,384 f
    unsigned short* Wrp    = (unsigned short*)(ws + 7222536);  // 32768 bf16
    unsigned short* h1b    = (unsigned short*)(ws + 7238920);  // NPAD*256 bf16 = 6,406,144 f
    float*          y2     = ws + 13645064;                    //   800,000
    // total: 14,445,064 floats = 57.8 MB

    hipMemsetAsync(cnt, 0, (size_t)N * sizeof(unsigned), stream);
    hipMemsetAsync(xb   + (size_t)N * FIN, 0, (size_t)(NPAD - N) * FIN * 2, stream);
    hipMemsetAsync(aggb + (size_t)N * FIN, 0, (size_t)(NPAD - N) * FIN * 2, stream);

    const int EB = (NE + 255) / 256;
    k_packW<<<32, 256, 0, stream>>>(W1l, W1r, Wlp, Wrp);
    k_castx<<<(N * FIN / 8) / 256, 256, 0, stream>>>(x, xb);     // 3125 blocks exact
    k_hist <<<EB, 256, 0, stream>>>(dstv, cnt);
    k_scan <<<1, 1024, 0, stream>>>(cnt, rowptr, cursor, scale);
    k_place<<<EB, 256, 0, stream>>>(srcv, dstv, cursor, srcs);

    k_agg1<<<(N * 64) / 256, 256, 0, stream>>>(xb, srcs, rowptr, scale, aggb);
    k_l1m <<<NPAD / 64, 256, 0, stream>>>(aggb, xb, Wlp, Wrp, b1, h1b);

    k_y2  <<<N / 16, 256, 0, stream>>>(h1b, W2l, y2);
    k_out <<<N / 16, 256, 0, stream>>>(h1b, y2, srcs, rowptr, scale, W2r, b2, out);
}

// Round 4
// 259.146 us; speedup vs baseline: 5.6324x; 1.4830x over previous
//
#include <hip/hip_runtime.h>
#include <hip/hip_bf16.h>

constexpr int N    = 50000;
constexpr int NPAD = 50048;          // padded to 64-row tiles (782*64)
constexpr int FIN  = 128;
constexpr int HID  = 256;
constexpr int NC   = 16;
constexpr int NE   = 600000;
constexpr int NBLK = (N + 255) / 256;   // 196 scan blocks (< 256)

using bf16x8 = __attribute__((ext_vector_type(8))) short;
using f32x4  = __attribute__((ext_vector_type(4))) float;

__device__ inline float bf2f(unsigned short u) {
    union { unsigned int i; float f; } v; v.i = (unsigned)u << 16; return v.f;
}
__device__ inline unsigned short f2bf(float f) {
    __hip_bfloat16 h = __float2bfloat16(f);
    return __builtin_bit_cast(unsigned short, h);
}

// ---------------------------------------------------------------------------
// Counting sort (CSR by dst): hist -> (bsum, scan2) -> place.
// ---------------------------------------------------------------------------
__global__ __launch_bounds__(256) void k_hist(const int* __restrict__ dstv,
                                              unsigned* __restrict__ cnt) {
    unsigned e = blockIdx.x * 256u + threadIdx.x;
    if (e < (unsigned)NE) atomicAdd(&cnt[dstv[e]], 1u);
}

// per-block sums of 256 counts
__global__ __launch_bounds__(256) void k_bsum(const unsigned* __restrict__ cnt,
                                              unsigned* __restrict__ bsum) {
    __shared__ unsigned red[256];
    const int t = threadIdx.x;
    unsigned i = blockIdx.x * 256u + t;
    red[t] = (i < (unsigned)N) ? cnt[i] : 0u;
    __syncthreads();
    for (int off = 128; off > 0; off >>= 1) {
        if (t < off) red[t] += red[t + off];
        __syncthreads();
    }
    if (t == 0) bsum[blockIdx.x] = red[0];
}

// per-block exclusive scan + cross-block base; emits rowptr/cursor/scale
__global__ __launch_bounds__(256) void k_scan2(const unsigned* __restrict__ cnt,
                                               const unsigned* __restrict__ bsum,
                                               unsigned* __restrict__ rowptr,
                                               unsigned* __restrict__ cursor,
                                               float* __restrict__ scale) {
    __shared__ unsigned red[256];
    __shared__ unsigned sc[256];
    const int t   = threadIdx.x;
    const int bid = blockIdx.x;

    // base = sum(bsum[0..bid)); NBLK < 256 so one element per thread
    red[t] = (t < bid) ? bsum[t] : 0u;
    __syncthreads();
    for (int off = 128; off > 0; off >>= 1) {
        if (t < off) red[t] += red[t + off];
        __syncthreads();
    }
    const unsigned base = red[0];

    // Hillis-Steele inclusive scan of this block's 256 counts
    unsigned i = bid * 256u + t;
    unsigned c = (i < (unsigned)N) ? cnt[i] : 0u;
    sc[t] = c;
    __syncthreads();
    for (int off = 1; off < 256; off <<= 1) {
        unsigned v = (t >= off) ? sc[t - off] : 0u;
        __syncthreads();
        sc[t] += v;
        __syncthreads();
    }
    const unsigned exc = base + sc[t] - c;
    if (i < (unsigned)N) {
        rowptr[i] = exc;
        cursor[i] = exc;
        scale[i]  = 1.0f / fmaxf((float)c, 1.0f);
    }
    if (bid == 0 && t == 0) rowptr[N] = (unsigned)NE;   // total edges is constant
}

__global__ __launch_bounds__(256) void k_place(const int* __restrict__ srcv,
                                               const int* __restrict__ dstv,
                                               unsigned* __restrict__ cursor,
                                               int* __restrict__ srcs) {
    unsigned e = blockIdx.x * 256u + threadIdx.x;
    if (e >= (unsigned)NE) return;
    unsigned pos = atomicAdd(&cursor[dstv[e]], 1u);
    srcs[pos] = srcv[e];
}

// ---------------------------------------------------------------------------
// x (f32) -> xb (bf16), 8 elems/thread. Grid covers exactly N*FIN/8.
// ---------------------------------------------------------------------------
__global__ __launch_bounds__(256) void k_castx(const float* __restrict__ x,
                                               unsigned short* __restrict__ xb) {
    size_t idx = (size_t)blockIdx.x * 256u + threadIdx.x;
    const float4 v0 = *reinterpret_cast<const float4*>(&x[idx * 8]);
    const float4 v1 = *reinterpret_cast<const float4*>(&x[idx * 8 + 4]);
    bf16x8 o;
    o[0] = (short)f2bf(v0.x); o[1] = (short)f2bf(v0.y);
    o[2] = (short)f2bf(v0.z); o[3] = (short)f2bf(v0.w);
    o[4] = (short)f2bf(v1.x); o[5] = (short)f2bf(v1.y);
    o[6] = (short)f2bf(v1.z); o[7] = (short)f2bf(v1.w);
    *reinterpret_cast<bf16x8*>(&xb[idx * 8]) = o;
}

// ---------------------------------------------------------------------------
// Pack W1l/W1r (f32 [128][256]) into MFMA operand order (bf16):
// Wp[((kk*256 + c)*4 + g)*8 + b] = W[(kk*32 + g*8 + b)][c]
// ---------------------------------------------------------------------------
__global__ __launch_bounds__(256) void k_packW(const float* __restrict__ Wl,
                                               const float* __restrict__ Wr,
                                               unsigned short* __restrict__ Wlp,
                                               unsigned short* __restrict__ Wrp) {
    unsigned id = blockIdx.x * 256u + threadIdx.x;    // 8192 total
    unsigned mat = id >> 12, kk = (id >> 10) & 3, c = (id >> 2) & 255, g = id & 3;
    const float* src = mat ? Wr : Wl;
    unsigned short* dst = mat ? Wrp : Wlp;
    bf16x8 o;
#pragma unroll
    for (int b = 0; b < 8; ++b)
        o[b] = (short)f2bf(src[(kk * 32 + g * 8 + b) * HID + c]);
    *reinterpret_cast<bf16x8*>(&dst[((kk * 256u + c) * 4u + g) * 8u]) = o;
}

// ---------------------------------------------------------------------------
// Layer-1 aggregation (gather): one wave per node, lane = 2 bf16 cols.
// ---------------------------------------------------------------------------
__global__ __launch_bounds__(256) void k_agg1(const unsigned short* __restrict__ xb,
                                              const int* __restrict__ srcs,
                                              const unsigned* __restrict__ rowptr,
                                              const float* __restrict__ scale,
                                              unsigned short* __restrict__ aggb) {
    const unsigned wid  = (blockIdx.x * 256u + threadIdx.x) >> 6;
    const unsigned lane = threadIdx.x & 63;
    if (wid >= (unsigned)N) return;
    const unsigned lo = rowptr[wid], hi = rowptr[wid + 1];
    float ax = 0.f, ay = 0.f;
    for (unsigned e = lo; e < hi; ++e) {
        const int s = srcs[e];
        unsigned v = *reinterpret_cast<const unsigned*>(&xb[(size_t)s * FIN + lane * 2]);
        ax += bf2f((unsigned short)(v & 0xffffu));
        ay += bf2f((unsigned short)(v >> 16));
    }
    const float sc = scale[wid];
    unsigned ov = (unsigned)f2bf(ax * sc) | ((unsigned)f2bf(ay * sc) << 16);
    *reinterpret_cast<unsigned*>(&aggb[(size_t)wid * FIN + lane * 2]) = ov;
}

// ---------------------------------------------------------------------------
// Layer-1 MFMA GEMM: h1 = relu(agg@W1l + x@W1r + b1), bf16 in/out, f32 acc.
// Block: 64 rows x 256 cols, 4 waves (each 64 cols). A staged in LDS with
// 16B-chunk XOR swizzle (2-way banks). k-permutation sigma(g,b)=8g+b applied
// identically to A and B (contraction is invariant to common k-perm).
// ---------------------------------------------------------------------------
__global__ __launch_bounds__(256) void k_l1m(const unsigned short* __restrict__ aggb,
                                             const unsigned short* __restrict__ xb,
                                             const unsigned short* __restrict__ Wlp,
                                             const unsigned short* __restrict__ Wrp,
                                             const float* __restrict__ b1,
                                             unsigned short* __restrict__ h1b) {
    __shared__ short sA[2][64 * FIN];
    const int t = threadIdx.x;
    const int wave = t >> 6, lane = t & 63;
    const int g = lane >> 4, lr = lane & 15;
    const size_t row0 = (size_t)blockIdx.x * 64;

    for (int mat = 0; mat < 2; ++mat) {
        const unsigned short* src = mat ? xb : aggb;
        for (int i = t; i < 64 * 16; i += 256) {
            int r = i >> 4, c = i & 15;
            bf16x8 v = *reinterpret_cast<const bf16x8*>(&src[(row0 + r) * FIN + c * 8]);
            int dc = c ^ (r & 7);
            *reinterpret_cast<bf16x8*>(&sA[mat][r * FIN + dc * 8]) = v;
        }
    }
    __syncthreads();

    f32x4 acc[4][4];
#pragma unroll
    for (int m = 0; m < 4; ++m)
#pragma unroll
        for (int n = 0; n < 4; ++n) acc[m][n] = (f32x4){0.f, 0.f, 0.f, 0.f};

#pragma unroll
    for (int kk = 0; kk < 4; ++kk) {
        bf16x8 bL[4], bR[4];
#pragma unroll
        for (int n = 0; n < 4; ++n) {
            int col = wave * 64 + n * 16 + lr;
            size_t off = ((size_t)(kk * 256 + col) * 4 + g) * 8;
            bL[n] = *reinterpret_cast<const bf16x8*>(&Wlp[off]);
            bR[n] = *reinterpret_cast<const bf16x8*>(&Wrp[off]);
        }
        bf16x8 aA[4], aX[4];
        const int chunk = (kk * 4 + g) ^ (lr & 7);
#pragma unroll
        for (int m = 0; m < 4; ++m) {
            int r = m * 16 + lr;
            aA[m] = *reinterpret_cast<const bf16x8*>(&sA[0][r * FIN + chunk * 8]);
            aX[m] = *reinterpret_cast<const bf16x8*>(&sA[1][r * FIN + chunk * 8]);
        }
#pragma unroll
        for (int m = 0; m < 4; ++m)
#pragma unroll
            for (int n = 0; n < 4; ++n) {
                acc[m][n] = __builtin_amdgcn_mfma_f32_16x16x32_bf16(aA[m], bL[n], acc[m][n], 0, 0, 0);
                acc[m][n] = __builtin_amdgcn_mfma_f32_16x16x32_bf16(aX[m], bR[n], acc[m][n], 0, 0, 0);
            }
    }

    // epilogue: +bias, relu, bf16 store. C/D map (m89): col=lane&15, row=4*(lane>>4)+reg
#pragma unroll
    for (int n = 0; n < 4; ++n) {
        int col = wave * 64 + n * 16 + lr;
        float bb = b1[col];
#pragma unroll
        for (int m = 0; m < 4; ++m) {
#pragma unroll
            for (int reg = 0; reg < 4; ++reg) {
                size_t r = row0 + m * 16 + g * 4 + reg;
                float z = acc[m][n][reg] + bb;
                h1b[r * HID + col] = f2bf(fmaxf(z, 0.f));
            }
        }
    }
}

// ---------------------------------------------------------------------------
// y2 = h1 @ W2_l   ([N,256]bf16 @ [256,16]f32)
// ---------------------------------------------------------------------------
__global__ __launch_bounds__(256) void k_y2(const unsigned short* __restrict__ h1b,
                                            const float* __restrict__ W,
                                            float* __restrict__ y2) {
    const int t = threadIdx.x, c = t & 15, nl = t >> 4;
    const size_t n = (size_t)blockIdx.x * 16 + nl;
    const unsigned short* hr = &h1b[n * HID];
    float z = 0.f;
    for (int k = 0; k < HID; ++k) z += bf2f(hr[k]) * W[k * NC + c];
    y2[n * NC + c] = z;
}

// ---------------------------------------------------------------------------
// out = log_softmax(gather(y2)/deg + b2 + h1@W2_r), layer-2 agg fused.
// ---------------------------------------------------------------------------
__global__ __launch_bounds__(256) void k_out(const unsigned short* __restrict__ h1b,
                                             const float* __restrict__ y2,
                                             const int* __restrict__ srcs,
                                             const unsigned* __restrict__ rowptr,
                                             const float* __restrict__ scale,
                                             const float* __restrict__ Wr,
                                             const float* __restrict__ b,
                                             float* __restrict__ out) {
    const int t = threadIdx.x, c = t & 15, nl = t >> 4;
    const size_t n = (size_t)blockIdx.x * 16 + nl;
    const unsigned lo = rowptr[n], hi = rowptr[n + 1];
    float gsum = 0.f;
    for (unsigned e = lo; e < hi; ++e)
        gsum += y2[(size_t)srcs[e] * NC + c];
    float z = gsum * scale[n] + b[c];
    const unsigned short* hr = &h1b[n * HID];
    for (int k = 0; k < HID; ++k)
        z += bf2f(hr[k]) * Wr[k * NC + c];

    float m = z;
    for (int off = 1; off < 16; off <<= 1)
        m = fmaxf(m, __shfl_xor(m, off, 16));
    float ex = expf(z - m);
    float s = ex;
    for (int off = 1; off < 16; off <<= 1)
        s += __shfl_xor(s, off, 16);
    out[n * NC + c] = (z - m) - logf(s);
}

// ---------------------------------------------------------------------------
extern "C" void kernel_launch(void* const* d_in, const int* in_sizes, int n_in,
                              void* d_out, int out_size, void* d_ws, size_t ws_size,
                              hipStream_t stream) {
    const float* x    = (const float*)d_in[0];
    const int*   ei   = (const int*)d_in[1];    // int32 on device (JAX x64 off)
    const int*   srcv = ei;
    const int*   dstv = ei + NE;
    const float* W1l  = (const float*)d_in[2];
    const float* W1r  = (const float*)d_in[3];
    const float* b1   = (const float*)d_in[4];
    const float* W2l  = (const float*)d_in[5];
    const float* W2r  = (const float*)d_in[6];
    const float* b2   = (const float*)d_in[7];
    float* out = (float*)d_out;

    // workspace layout (float offsets; all bf16x8 users 16B-aligned)
    float*          ws     = (float*)d_ws;
    float*          scale  = ws;                               //    50,000
    unsigned*       cnt    = (unsigned*)(ws + 50000);          //    50,000
    unsigned*       rowptr = (unsigned*)(ws + 100000);         //    50,004 (pad)
    unsigned*       cursor = (unsigned*)(ws + 150004);         //    50,000
    unsigned*       bsum   = (unsigned*)(ws + 200004);         //       256 (pad)
    int*            srcs   = (int*)(ws + 200260);              //   600,000
    unsigned short* xb     = (unsigned short*)(ws + 800260);   // NPAD*128 bf16 = 3,203,072 f
    unsigned short* aggb   = (unsigned short*)(ws + 4003332);  // NPAD*128 bf16
    unsigned short* Wlp    = (unsigned short*)(ws + 7206404);  // 32768 bf16 = 16,384 f
    unsigned short* Wrp    = (unsigned short*)(ws + 7222788);  // 32768 bf16
    unsigned short* h1b    = (unsigned short*)(ws + 7239172);  // NPAD*256 bf16 = 6,406,144 f
    float*          y2     = ws + 13645316;                    //   800,000
    // total: 14,445,316 floats = 57.8 MB

    hipMemsetAsync(cnt, 0, (size_t)N * sizeof(unsigned), stream);
    hipMemsetAsync(xb   + (size_t)N * FIN, 0, (size_t)(NPAD - N) * FIN * 2, stream);
    hipMemsetAsync(aggb + (size_t)N * FIN, 0, (size_t)(NPAD - N) * FIN * 2, stream);

    const int EB = (NE + 255) / 256;
    k_packW<<<32, 256, 0, stream>>>(W1l, W1r, Wlp, Wrp);
    k_castx<<<(N * FIN / 8) / 256, 256, 0, stream>>>(x, xb);     // 3125 blocks exact
    k_hist <<<EB, 256, 0, stream>>>(dstv, cnt);
    k_bsum <<<NBLK, 256, 0, stream>>>(cnt, bsum);
    k_scan2<<<NBLK, 256, 0, stream>>>(cnt, bsum, rowptr, cursor, scale);
    k_place<<<EB, 256, 0, stream>>>(srcv, dstv, cursor, srcs);

    k_agg1<<<(N * 64) / 256, 256, 0, stream>>>(xb, srcs, rowptr, scale, aggb);
    k_l1m <<<NPAD / 64, 256, 0, stream>>>(aggb, xb, Wlp, Wrp, b1, h1b);

    k_y2  <<<N / 16, 256, 0, stream>>>(h1b, W2l, y2);
    k_out <<<N / 16, 256, 0, stream>>>(h1b, y2, srcs, rowptr, scale, W2r, b2, out);
}